// Round 10
// baseline (114.973 us; speedup 1.0000x reference)
//
#include <hip/hip_runtime.h>
#include <hip/hip_bf16.h>

// (N,C,K,H,W) = (4,3,21,128,128), SCALE=0.5 -> Ho=Wo=64, P=4096
// loss = -(W/N) * sum_{n,p,q} gate_p * exp(-0.5*d2) * (S_p . S_q)
// Triangle tiles; per 128x128 tile all weighting folded into two MFMA chains:
//   c1 = gS_p·S_q + S_p·gS_q = (gp+gq)(S_p·S_q)      [K=48: A=[gS|S], B=[S|gS], 3 MFMAs]
//   c2 = f_p·f_q - 0.5sq_p - 0.5sq_q = -0.5*d2 EXACT [2 MFMAs, f16 hi/lo + sq hi/lo]
//     featA = [hi(5),sqh,sql,1 | lo(5),0,0,1]        (stored, 32B)
//     featB1= [hi(5),1,1,sqh   | hi(5),0,0,sql]      (built in-register from featA)
//     featB2= [lo(5),0,0,0     | lo(5),0,0,0]        (built in-register from featA)
//   w = exp2(min(log2e*c2,0)); acc += w*c1           (epilogue: no LDS)
// total = sum_{i<j} T_ij + 0.5 sum_i T_ii ; out = -1e-7/N * total.
//
// R10 = R9 + layout fix: R9 put PART/CNT *inside* the F region (F ends at
// 0x180000+16384*32 = 0x200000; PART was 0x1C0000) -> prep's F-record for
// pixel 8464 overwrote cnt -> last-block reduction never fired -> out=0.
// PART/CNT now start at 0x200000, past all data regions.

typedef _Float16 v8h __attribute__((ext_vector_type(8)));
typedef float v16f __attribute__((ext_vector_type(16)));

#define NIMG 4
#define KCH 21
#define HIN 128
#define WIN 128
#define PPX 4096
#define TPB 32                 // 128-tiles per axis
#define TRI 528                // TPB*(TPB+1)/2
#define NBLK (NIMG * TRI)      // 2112

#define WS_S_OFF 0x000000      // 96B/pixel [gS(24 f16)|S(24 f16)]  -> ends 0x180000
#define WS_F_OFF 0x180000      // 32B/pixel featA                   -> ends 0x200000
#define PART_OFF 0x200000      // 2112 f32                          -> ends 0x202100
#define CNT_OFF  0x202200

#define LOG2E 1.44269504088896341f

__device__ __forceinline__ float fexp2(float x) {
#if __has_builtin(__builtin_amdgcn_exp2f)
    return __builtin_amdgcn_exp2f(x);
#else
    return __expf(x * 0.69314718055994531f);
#endif
}

// ---- prep: per pixel, one 96B S-record and one 32B F-record ----
__global__ __launch_bounds__(256) void prep_kernel(
    const float* __restrict__ img, const float* __restrict__ seg,
    const float* __restrict__ roi, const int* __restrict__ lbl,
    char* __restrict__ ws)
{
    int gid = blockIdx.x * 256 + threadIdx.x;     // 16384
    if (gid == 0) *(unsigned*)(ws + CNT_OFF) = 0u;
    int n = gid >> 12, p = gid & (PPX - 1);
    int y = p >> 6, x = p & 63, iy = 2 * y, ix = 2 * x;
    const float inv_rgb = 1.0f / 15.0f, inv_sxy = 1.0f / 50.0f;

    float rv = roi[((size_t)n * HIN + iy) * WIN + ix];
    int   lb = lbl[((size_t)n * HIN + iy) * WIN + ix];

    float sv[KCH]; float maxs = 0.0f;
    #pragma unroll
    for (int k = 0; k < KCH; k++) {
        const float* sp = seg + ((((size_t)n * KCH + k) * HIN + iy) * WIN + ix);
        float2 a = *(const float2*)sp;
        float2 c = *(const float2*)(sp + WIN);
        float s = 0.25f * (a.x + a.y + c.x + c.y);
        maxs = fmaxf(maxs, s);
        sv[k] = s * rv;
    }
    float gate = (lb == 255) ? 1.0f : fmaxf(rv - maxs, 0.0f);

    union { float4 q[6]; _Float16 e[48]; } rs;
    #pragma unroll
    for (int k = 0; k < KCH; k++) {
        rs.e[k] = (_Float16)(sv[k] * gate);       // gS
        rs.e[24 + k] = (_Float16)sv[k];           // S
    }
    #pragma unroll
    for (int k = KCH; k < 24; k++) { rs.e[k] = (_Float16)0.f; rs.e[24 + k] = (_Float16)0.f; }

    float f[5];
    f[0] = (float)x * inv_sxy;
    f[1] = (float)y * inv_sxy;
    f[2] = img[(((size_t)n * 3 + 0) * HIN + iy) * WIN + ix] * inv_rgb;
    f[3] = img[(((size_t)n * 3 + 1) * HIN + iy) * WIN + ix] * inv_rgb;
    f[4] = img[(((size_t)n * 3 + 2) * HIN + iy) * WIN + ix] * inv_rgb;

    _Float16 hi[5], lo[5];
    float sq = 0.f;
    #pragma unroll
    for (int u = 0; u < 5; u++) {
        hi[u] = (_Float16)f[u];
        lo[u] = (_Float16)(f[u] - (float)hi[u]);
        float fe = (float)hi[u] + (float)lo[u];
        sq = fmaf(fe, fe, sq);
    }
    float sqv = -0.5f * sq;
    _Float16 sqh = (_Float16)sqv;
    _Float16 sql = (_Float16)(sqv - (float)sqh);
    const _Float16 h0 = (_Float16)0.f, h1 = (_Float16)1.f;

    union { float4 q[2]; _Float16 e[16]; } rf;
    #pragma unroll
    for (int u = 0; u < 5; u++) { rf.e[u] = hi[u]; rf.e[8 + u] = lo[u]; }
    rf.e[5] = sqh; rf.e[6] = sql; rf.e[7] = h1;
    rf.e[13] = h0; rf.e[14] = h0; rf.e[15] = h1;

    float4* ds = (float4*)(ws + WS_S_OFF + (size_t)gid * 96);
    #pragma unroll
    for (int u = 0; u < 6; u++) ds[u] = rs.q[u];
    float4* df = (float4*)(ws + WS_F_OFF + (size_t)gid * 32);
    df[0] = rf.q[0]; df[1] = rf.q[1];
}

// ---- pairs: block = upper-tri 128x128 tile; waves 2x2 over 64x64; 32x32 subtiles ----
// LDS: S 256 rows x 104B stride (26 dw, 2-way only = free); F 256 rows x 40B stride
#define LSTR 104
#define FSTR 40
#define SREG_O 0
#define FREG_O 26624
#define RED_O  36864
#define FLAG_O 36880
#define LDS_BYTES 36896

__global__ __launch_bounds__(256)
__attribute__((amdgpu_waves_per_eu(1, 4)))
void pairs_kernel(
    const char* __restrict__ ws, float* __restrict__ part,
    unsigned* __restrict__ cnt, float* __restrict__ out)
{
    __shared__ __align__(16) char smem[LDS_BYTES];
    int b = blockIdx.x;
    int n = b / TRI, r = b - n * TRI;
    int i = 0, rowlen = TPB;
    while (r >= rowlen) { r -= rowlen; rowlen--; i++; }
    int j = i + r;                                 // i <= j
    bool diag = (i == j);

    int t = threadIdx.x;
    int lane = t & 63, half = lane >> 5, lr = lane & 31, wv = t >> 6;
    int wq = wv & 1, wp = wv >> 1;

    // ---- stage: i-tile -> rows 0..127, j-tile -> rows 128..255 ----
    {
        const float4* gsi = (const float4*)(ws + WS_S_OFF) + (size_t)(n * PPX + i * 128) * 6;
        #pragma unroll
        for (int k = 0; k < 3; k++) {
            int v = t + k * 256;                   // 0..767
            int row = v / 6, off = v - row * 6;
            float4 vs = gsi[v];
            char* dS = smem + SREG_O + row * LSTR + off * 16;
            *(float2*)dS = make_float2(vs.x, vs.y);
            *(float2*)(dS + 8) = make_float2(vs.z, vs.w);
        }
        const float4* gfi = (const float4*)(ws + WS_F_OFF) + (size_t)(n * PPX + i * 128) * 2;
        {
            int row = t >> 1, off = t & 1;         // 256 threads cover 128 rows x 2
            float4 vf = gfi[t];
            char* dF = smem + FREG_O + row * FSTR + off * 16;
            *(float2*)dF = make_float2(vf.x, vf.y);
            *(float2*)(dF + 8) = make_float2(vf.z, vf.w);
        }
        if (!diag) {
            const float4* gsj = (const float4*)(ws + WS_S_OFF) + (size_t)(n * PPX + j * 128) * 6;
            #pragma unroll
            for (int k = 0; k < 3; k++) {
                int v = t + k * 256;
                int row = v / 6, off = v - row * 6;
                float4 vs = gsj[v];
                char* dS = smem + SREG_O + (128 + row) * LSTR + off * 16;
                *(float2*)dS = make_float2(vs.x, vs.y);
                *(float2*)(dS + 8) = make_float2(vs.z, vs.w);
            }
            const float4* gfj = (const float4*)(ws + WS_F_OFF) + (size_t)(n * PPX + j * 128) * 2;
            int row = t >> 1, off = t & 1;
            float4 vf = gfj[t];
            char* dF = smem + FREG_O + (128 + row) * FSTR + off * 16;
            *(float2*)dF = make_float2(vf.x, vf.y);
            *(float2*)(dF + 8) = make_float2(vf.z, vf.w);
        }
    }
    __syncthreads();

    int jrow0 = diag ? 0 : 128;
    const _Float16 selA = half ? (_Float16)0.f : (_Float16)1.f;
    float ac0 = 0.f, ac1 = 0.f, ac2 = 0.f, ac3 = 0.f;

    #pragma unroll
    for (int sp = 0; sp < 2; sp++) {
        // A-side fragments (p-row), k = half*8 within each K-slice
        int pr = wp * 64 + sp * 32 + lr;
        const char* sb = smem + SREG_O + pr * LSTR;
        const char* fb = smem + FREG_O + pr * FSTR;
        union { v8h h; float2 f[2]; } A0, A1, A2, Af;
        A0.f[0] = *(const float2*)(sb + half * 16);         // gS[0:16]
        A0.f[1] = *(const float2*)(sb + half * 16 + 8);
        A1.f[0] = *(const float2*)(sb + 32 + half * 16);    // gS[16:24]|S[0:8]
        A1.f[1] = *(const float2*)(sb + 32 + half * 16 + 8);
        A2.f[0] = *(const float2*)(sb + 64 + half * 16);    // S[8:24]
        A2.f[1] = *(const float2*)(sb + 64 + half * 16 + 8);
        Af.f[0] = *(const float2*)(fb + half * 16);         // featA half
        Af.f[1] = *(const float2*)(fb + half * 16 + 8);

        #pragma unroll
        for (int s = 0; s < 2; s++) {
            // B-side fragments (q-col)
            int cr = jrow0 + wq * 64 + s * 32 + lr;
            const char* cb = smem + SREG_O + cr * LSTR;
            const char* gb = smem + FREG_O + cr * FSTR;
            union { v8h h; float2 f[2]; } B0, B1, B2;
            union { v8h h; float2 f[2]; _Float16 e[8]; } U, L;
            B0.f[0] = *(const float2*)(cb + 48 + half * 16);        // S[0:16]
            B0.f[1] = *(const float2*)(cb + 48 + half * 16 + 8);
            int o1 = half ? 0 : 80;                                 // S[16:24]|gS[0:8]
            B1.f[0] = *(const float2*)(cb + o1);
            B1.f[1] = *(const float2*)(cb + o1 + 8);
            B2.f[0] = *(const float2*)(cb + 16 + half * 16);        // gS[8:24]
            B2.f[1] = *(const float2*)(cb + 16 + half * 16 + 8);
            U.f[0] = *(const float2*)(gb);      U.f[1] = *(const float2*)(gb + 8);   // [hi5,sqh,sql,1]
            L.f[0] = *(const float2*)(gb + 16); L.f[1] = *(const float2*)(gb + 24);  // [lo5,0,0,1]

            // featB1 = [hi5,1,1,sqh | hi5,0,0,sql], featB2 = [lo5,0,0,0 | lo5,0,0,0]
            union { v8h h; _Float16 e[8]; } Bf1, Bf2;
            Bf1.h = U.h;
            Bf1.e[5] = selA; Bf1.e[6] = selA;
            Bf1.e[7] = half ? U.e[6] : U.e[5];
            Bf2.h = L.h;
            Bf2.e[7] = (_Float16)0.f;

            v16f z = {0.f,0.f,0.f,0.f,0.f,0.f,0.f,0.f,0.f,0.f,0.f,0.f,0.f,0.f,0.f,0.f};
            v16f c2 = __builtin_amdgcn_mfma_f32_32x32x16_f16(Af.h, Bf1.h, z, 0, 0, 0);
            c2 = __builtin_amdgcn_mfma_f32_32x32x16_f16(Af.h, Bf2.h, c2, 0, 0, 0);
            v16f c1 = __builtin_amdgcn_mfma_f32_32x32x16_f16(A0.h, B0.h, z, 0, 0, 0);
            c1 = __builtin_amdgcn_mfma_f32_32x32x16_f16(A1.h, B1.h, c1, 0, 0, 0);
            c1 = __builtin_amdgcn_mfma_f32_32x32x16_f16(A2.h, B2.h, c1, 0, 0, 0);

            #pragma unroll
            for (int rr = 0; rr < 16; rr++) {
                float arg = fminf(LOG2E * c2[rr], 0.0f);   // c2 = -0.5*d2 (exact)
                float w = fexp2(arg);
                if ((rr & 3) == 0)      ac0 = fmaf(w, c1[rr], ac0);
                else if ((rr & 3) == 1) ac1 = fmaf(w, c1[rr], ac1);
                else if ((rr & 3) == 2) ac2 = fmaf(w, c1[rr], ac2);
                else                    ac3 = fmaf(w, c1[rr], ac3);
            }
        }
    }

    float acc = (ac0 + ac1) + (ac2 + ac3);
    #pragma unroll
    for (int off = 32; off > 0; off >>= 1) acc += __shfl_down(acc, off, 64);
    float* wred = (float*)(smem + RED_O);
    int* flag = (int*)(smem + FLAG_O);
    if ((t & 63) == 0) wred[t >> 6] = acc;
    __syncthreads();
    if (t == 0) {
        float partial = (wred[0] + wred[1]) + (wred[2] + wred[3]);
        if (diag) partial *= 0.5f;                 // diag tiles double-count (p,q)/(q,p)
        part[b] = partial;
        __threadfence();
        unsigned old = atomicAdd(cnt, 1u);
        *flag = (old == NBLK - 1) ? 1 : 0;
    }
    __syncthreads();

    if (*flag) {
        __threadfence();
        float v = 0.f;
        #pragma unroll
        for (int k = 0; k < 9; k++) {
            int idx = t + k * 256;
            if (idx < NBLK)
                v += __hip_atomic_load(&part[idx], __ATOMIC_RELAXED,
                                       __HIP_MEMORY_SCOPE_AGENT);
        }
        float* red = (float*)smem;
        red[t] = v;
        __syncthreads();
        #pragma unroll
        for (int off = 128; off > 0; off >>= 1) {
            if (t < off) red[t] += red[t + off];
            __syncthreads();
        }
        if (t == 0) out[0] = red[0] * (-1e-7f / (float)NIMG);
    }
}

extern "C" void kernel_launch(void* const* d_in, const int* in_sizes, int n_in,
                              void* d_out, int out_size, void* d_ws, size_t ws_size,
                              hipStream_t stream) {
    const float* images = (const float*)d_in[0];   // [4,3,128,128]
    const float* seg    = (const float*)d_in[1];   // [4,21,128,128]
    const float* rois   = (const float*)d_in[2];   // [4,128,128]
    const int*   lbl    = (const int*)d_in[3];     // [4,1,128,128]
    float* out = (float*)d_out;
    char*  ws  = (char*)d_ws;
    float* part = (float*)(ws + PART_OFF);
    unsigned* cnt = (unsigned*)(ws + CNT_OFF);

    hipLaunchKernelGGL(prep_kernel, dim3((NIMG * PPX) / 256), dim3(256), 0, stream,
                       images, seg, rois, lbl, ws);
    hipLaunchKernelGGL(pairs_kernel, dim3(NBLK), dim3(256), 0, stream,
                       (const char*)ws, part, cnt, out);
}

// Round 11
// 82.491 us; speedup vs baseline: 1.3938x; 1.3938x over previous
//
#include <hip/hip_runtime.h>
#include <hip/hip_bf16.h>

// (N,C,K,H,W) = (4,3,21,128,128), SCALE=0.5 -> Ho=Wo=64, P=4096
// loss = -(W/N) * sum_{n,p,q} gate_p * exp(-0.5*d2) * (S_p . S_q)
// Triangle tiles; per 128x128 tile all weighting folded into two MFMA chains:
//   c1 = gS_p·S_q + S_p·gS_q = (gp+gq)(S_p·S_q)      [K=48: A=[gS|S], B=[S|gS], 3 MFMAs]
//   c2 = f_p·f_q - 0.5sq_p - 0.5sq_q = -0.5*d2 EXACT [2 MFMAs, f16 hi/lo + sq hi/lo]
//     featA = [hi(5),sqh,sql,1 | lo(5),0,0,1]        (stored, 32B)
//     featB1= [hi(5),1,1,sqh   | hi(5),0,0,sql]      (built in-register from featA)
//     featB2= [lo(5),0,0,0     | lo(5),0,0,0]        (built in-register from featA)
//   w = exp2(min(log2e*c2,0)); acc += w*c1           (epilogue: no LDS)
// total = sum_{i<j} T_ij + 0.5 sum_i T_ii ; out = -1e-7/N * total.
//
// R11: drop the per-block __threadfence + device-atomic last-block reduction
// (fence forces L2 writeback per block on non-coherent XCD L2s -> measured
// R6/R7/R10 all ~51-79us vs R8's ~21us without it). Separate deterministic
// finalize kernel instead (R8-proven). Keep R10's 36.9KB LDS (4 blocks/CU),
// in-register featB, 4 interleaved accumulators.

typedef _Float16 v8h __attribute__((ext_vector_type(8)));
typedef float v16f __attribute__((ext_vector_type(16)));

#define NIMG 4
#define KCH 21
#define HIN 128
#define WIN 128
#define PPX 4096
#define TPB 32                 // 128-tiles per axis
#define TRI 528                // TPB*(TPB+1)/2
#define NBLK (NIMG * TRI)      // 2112

#define WS_S_OFF 0x000000      // 96B/pixel [gS(24 f16)|S(24 f16)]  -> ends 0x180000
#define WS_F_OFF 0x180000      // 32B/pixel featA                   -> ends 0x200000
#define PART_OFF 0x200000      // 2112 f32

#define LOG2E 1.44269504088896341f

__device__ __forceinline__ float fexp2(float x) {
#if __has_builtin(__builtin_amdgcn_exp2f)
    return __builtin_amdgcn_exp2f(x);
#else
    return __expf(x * 0.69314718055994531f);
#endif
}

// ---- prep: per pixel, one 96B S-record and one 32B F-record ----
__global__ __launch_bounds__(256) void prep_kernel(
    const float* __restrict__ img, const float* __restrict__ seg,
    const float* __restrict__ roi, const int* __restrict__ lbl,
    char* __restrict__ ws)
{
    int gid = blockIdx.x * 256 + threadIdx.x;     // 16384
    int n = gid >> 12, p = gid & (PPX - 1);
    int y = p >> 6, x = p & 63, iy = 2 * y, ix = 2 * x;
    const float inv_rgb = 1.0f / 15.0f, inv_sxy = 1.0f / 50.0f;

    float rv = roi[((size_t)n * HIN + iy) * WIN + ix];
    int   lb = lbl[((size_t)n * HIN + iy) * WIN + ix];

    float sv[KCH]; float maxs = 0.0f;
    #pragma unroll
    for (int k = 0; k < KCH; k++) {
        const float* sp = seg + ((((size_t)n * KCH + k) * HIN + iy) * WIN + ix);
        float2 a = *(const float2*)sp;
        float2 c = *(const float2*)(sp + WIN);
        float s = 0.25f * (a.x + a.y + c.x + c.y);
        maxs = fmaxf(maxs, s);
        sv[k] = s * rv;
    }
    float gate = (lb == 255) ? 1.0f : fmaxf(rv - maxs, 0.0f);

    union { float4 q[6]; _Float16 e[48]; } rs;
    #pragma unroll
    for (int k = 0; k < KCH; k++) {
        rs.e[k] = (_Float16)(sv[k] * gate);       // gS
        rs.e[24 + k] = (_Float16)sv[k];           // S
    }
    #pragma unroll
    for (int k = KCH; k < 24; k++) { rs.e[k] = (_Float16)0.f; rs.e[24 + k] = (_Float16)0.f; }

    float f[5];
    f[0] = (float)x * inv_sxy;
    f[1] = (float)y * inv_sxy;
    f[2] = img[(((size_t)n * 3 + 0) * HIN + iy) * WIN + ix] * inv_rgb;
    f[3] = img[(((size_t)n * 3 + 1) * HIN + iy) * WIN + ix] * inv_rgb;
    f[4] = img[(((size_t)n * 3 + 2) * HIN + iy) * WIN + ix] * inv_rgb;

    _Float16 hi[5], lo[5];
    float sq = 0.f;
    #pragma unroll
    for (int u = 0; u < 5; u++) {
        hi[u] = (_Float16)f[u];
        lo[u] = (_Float16)(f[u] - (float)hi[u]);
        float fe = (float)hi[u] + (float)lo[u];
        sq = fmaf(fe, fe, sq);
    }
    float sqv = -0.5f * sq;
    _Float16 sqh = (_Float16)sqv;
    _Float16 sql = (_Float16)(sqv - (float)sqh);
    const _Float16 h0 = (_Float16)0.f, h1 = (_Float16)1.f;

    union { float4 q[2]; _Float16 e[16]; } rf;
    #pragma unroll
    for (int u = 0; u < 5; u++) { rf.e[u] = hi[u]; rf.e[8 + u] = lo[u]; }
    rf.e[5] = sqh; rf.e[6] = sql; rf.e[7] = h1;
    rf.e[13] = h0; rf.e[14] = h0; rf.e[15] = h1;

    float4* ds = (float4*)(ws + WS_S_OFF + (size_t)gid * 96);
    #pragma unroll
    for (int u = 0; u < 6; u++) ds[u] = rs.q[u];
    float4* df = (float4*)(ws + WS_F_OFF + (size_t)gid * 32);
    df[0] = rf.q[0]; df[1] = rf.q[1];
}

// ---- pairs: block = upper-tri 128x128 tile; waves 2x2 over 64x64; 32x32 subtiles ----
// LDS: S 256 rows x 104B stride (26 dw, 2-way only = free); F 256 rows x 40B stride
#define LSTR 104
#define FSTR 40
#define SREG_O 0
#define FREG_O 26624
#define RED_O  36864
#define LDS_BYTES 36880

__global__ __launch_bounds__(256)
__attribute__((amdgpu_waves_per_eu(1, 4)))
void pairs_kernel(
    const char* __restrict__ ws, float* __restrict__ part)
{
    __shared__ __align__(16) char smem[LDS_BYTES];
    int b = blockIdx.x;
    int n = b / TRI, r = b - n * TRI;
    int i = 0, rowlen = TPB;
    while (r >= rowlen) { r -= rowlen; rowlen--; i++; }
    int j = i + r;                                 // i <= j
    bool diag = (i == j);

    int t = threadIdx.x;
    int lane = t & 63, half = lane >> 5, lr = lane & 31, wv = t >> 6;
    int wq = wv & 1, wp = wv >> 1;

    // ---- stage: i-tile -> rows 0..127, j-tile -> rows 128..255 ----
    {
        const float4* gsi = (const float4*)(ws + WS_S_OFF) + (size_t)(n * PPX + i * 128) * 6;
        #pragma unroll
        for (int k = 0; k < 3; k++) {
            int v = t + k * 256;                   // 0..767
            int row = v / 6, off = v - row * 6;
            float4 vs = gsi[v];
            char* dS = smem + SREG_O + row * LSTR + off * 16;
            *(float2*)dS = make_float2(vs.x, vs.y);
            *(float2*)(dS + 8) = make_float2(vs.z, vs.w);
        }
        const float4* gfi = (const float4*)(ws + WS_F_OFF) + (size_t)(n * PPX + i * 128) * 2;
        {
            int row = t >> 1, off = t & 1;         // 256 threads cover 128 rows x 2
            float4 vf = gfi[t];
            char* dF = smem + FREG_O + row * FSTR + off * 16;
            *(float2*)dF = make_float2(vf.x, vf.y);
            *(float2*)(dF + 8) = make_float2(vf.z, vf.w);
        }
        if (!diag) {
            const float4* gsj = (const float4*)(ws + WS_S_OFF) + (size_t)(n * PPX + j * 128) * 6;
            #pragma unroll
            for (int k = 0; k < 3; k++) {
                int v = t + k * 256;
                int row = v / 6, off = v - row * 6;
                float4 vs = gsj[v];
                char* dS = smem + SREG_O + (128 + row) * LSTR + off * 16;
                *(float2*)dS = make_float2(vs.x, vs.y);
                *(float2*)(dS + 8) = make_float2(vs.z, vs.w);
            }
            const float4* gfj = (const float4*)(ws + WS_F_OFF) + (size_t)(n * PPX + j * 128) * 2;
            int row = t >> 1, off = t & 1;
            float4 vf = gfj[t];
            char* dF = smem + FREG_O + (128 + row) * FSTR + off * 16;
            *(float2*)dF = make_float2(vf.x, vf.y);
            *(float2*)(dF + 8) = make_float2(vf.z, vf.w);
        }
    }
    __syncthreads();

    int jrow0 = diag ? 0 : 128;
    const _Float16 selA = half ? (_Float16)0.f : (_Float16)1.f;
    float ac0 = 0.f, ac1 = 0.f, ac2 = 0.f, ac3 = 0.f;

    #pragma unroll
    for (int sp = 0; sp < 2; sp++) {
        // A-side fragments (p-row), k = half*8 within each K-slice
        int pr = wp * 64 + sp * 32 + lr;
        const char* sb = smem + SREG_O + pr * LSTR;
        const char* fb = smem + FREG_O + pr * FSTR;
        union { v8h h; float2 f[2]; } A0, A1, A2, Af;
        A0.f[0] = *(const float2*)(sb + half * 16);         // gS[0:16]
        A0.f[1] = *(const float2*)(sb + half * 16 + 8);
        A1.f[0] = *(const float2*)(sb + 32 + half * 16);    // gS[16:24]|S[0:8]
        A1.f[1] = *(const float2*)(sb + 32 + half * 16 + 8);
        A2.f[0] = *(const float2*)(sb + 64 + half * 16);    // S[8:24]
        A2.f[1] = *(const float2*)(sb + 64 + half * 16 + 8);
        Af.f[0] = *(const float2*)(fb + half * 16);         // featA half
        Af.f[1] = *(const float2*)(fb + half * 16 + 8);

        #pragma unroll
        for (int s = 0; s < 2; s++) {
            // B-side fragments (q-col)
            int cr = jrow0 + wq * 64 + s * 32 + lr;
            const char* cb = smem + SREG_O + cr * LSTR;
            const char* gb = smem + FREG_O + cr * FSTR;
            union { v8h h; float2 f[2]; } B0, B1, B2;
            union { v8h h; float2 f[2]; _Float16 e[8]; } U, L;
            B0.f[0] = *(const float2*)(cb + 48 + half * 16);        // S[0:16]
            B0.f[1] = *(const float2*)(cb + 48 + half * 16 + 8);
            int o1 = half ? 0 : 80;                                 // S[16:24]|gS[0:8]
            B1.f[0] = *(const float2*)(cb + o1);
            B1.f[1] = *(const float2*)(cb + o1 + 8);
            B2.f[0] = *(const float2*)(cb + 16 + half * 16);        // gS[8:24]
            B2.f[1] = *(const float2*)(cb + 16 + half * 16 + 8);
            U.f[0] = *(const float2*)(gb);      U.f[1] = *(const float2*)(gb + 8);   // [hi5,sqh,sql,1]
            L.f[0] = *(const float2*)(gb + 16); L.f[1] = *(const float2*)(gb + 24);  // [lo5,0,0,1]

            // featB1 = [hi5,1,1,sqh | hi5,0,0,sql], featB2 = [lo5,0,0,0 | lo5,0,0,0]
            union { v8h h; _Float16 e[8]; } Bf1, Bf2;
            Bf1.h = U.h;
            Bf1.e[5] = selA; Bf1.e[6] = selA;
            Bf1.e[7] = half ? U.e[6] : U.e[5];
            Bf2.h = L.h;
            Bf2.e[7] = (_Float16)0.f;

            v16f z = {0.f,0.f,0.f,0.f,0.f,0.f,0.f,0.f,0.f,0.f,0.f,0.f,0.f,0.f,0.f,0.f};
            v16f c2 = __builtin_amdgcn_mfma_f32_32x32x16_f16(Af.h, Bf1.h, z, 0, 0, 0);
            c2 = __builtin_amdgcn_mfma_f32_32x32x16_f16(Af.h, Bf2.h, c2, 0, 0, 0);
            v16f c1 = __builtin_amdgcn_mfma_f32_32x32x16_f16(A0.h, B0.h, z, 0, 0, 0);
            c1 = __builtin_amdgcn_mfma_f32_32x32x16_f16(A1.h, B1.h, c1, 0, 0, 0);
            c1 = __builtin_amdgcn_mfma_f32_32x32x16_f16(A2.h, B2.h, c1, 0, 0, 0);

            #pragma unroll
            for (int rr = 0; rr < 16; rr++) {
                float arg = fminf(LOG2E * c2[rr], 0.0f);   // c2 = -0.5*d2 (exact)
                float w = fexp2(arg);
                if ((rr & 3) == 0)      ac0 = fmaf(w, c1[rr], ac0);
                else if ((rr & 3) == 1) ac1 = fmaf(w, c1[rr], ac1);
                else if ((rr & 3) == 2) ac2 = fmaf(w, c1[rr], ac2);
                else                    ac3 = fmaf(w, c1[rr], ac3);
            }
        }
    }

    float acc = (ac0 + ac1) + (ac2 + ac3);
    #pragma unroll
    for (int off = 32; off > 0; off >>= 1) acc += __shfl_down(acc, off, 64);
    float* wred = (float*)(smem + RED_O);
    if ((t & 63) == 0) wred[t >> 6] = acc;
    __syncthreads();
    if (t == 0) {
        float partial = (wred[0] + wred[1]) + (wred[2] + wred[3]);
        if (diag) partial *= 0.5f;                 // diag tiles double-count (p,q)/(q,p)
        part[b] = partial;
    }
}

// ---- finalize: deterministic fixed-tree sum of 2112 partials ----
__global__ __launch_bounds__(256) void finalize_kernel(
    const float* __restrict__ part, float* __restrict__ out)
{
    __shared__ float s[256];
    int t = threadIdx.x;
    float v = 0.f;
    #pragma unroll
    for (int k = 0; k < 9; k++) {
        int idx = t + k * 256;
        if (idx < NBLK) v += part[idx];
    }
    s[t] = v;
    __syncthreads();
    #pragma unroll
    for (int off = 128; off > 0; off >>= 1) {
        if (t < off) s[t] += s[t + off];
        __syncthreads();
    }
    if (t == 0) out[0] = s[0] * (-1e-7f / (float)NIMG);
}

extern "C" void kernel_launch(void* const* d_in, const int* in_sizes, int n_in,
                              void* d_out, int out_size, void* d_ws, size_t ws_size,
                              hipStream_t stream) {
    const float* images = (const float*)d_in[0];   // [4,3,128,128]
    const float* seg    = (const float*)d_in[1];   // [4,21,128,128]
    const float* rois   = (const float*)d_in[2];   // [4,128,128]
    const int*   lbl    = (const int*)d_in[3];     // [4,1,128,128]
    float* out = (float*)d_out;
    char*  ws  = (char*)d_ws;
    float* part = (float*)(ws + PART_OFF);

    hipLaunchKernelGGL(prep_kernel, dim3((NIMG * PPX) / 256), dim3(256), 0, stream,
                       images, seg, rois, lbl, ws);
    hipLaunchKernelGGL(pairs_kernel, dim3(NBLK), dim3(256), 0, stream,
                       (const char*)ws, part);
    hipLaunchKernelGGL(finalize_kernel, dim3(1), dim3(256), 0, stream,
                       (const float*)part, out);
}